// Round 4
// baseline (988.487 us; speedup 1.0000x reference)
//
#include <hip/hip_runtime.h>

#define N_PTS 16384
#define CIN 128
#define COUT 256
#define KNN 20
#define NKTOT (N_PTS*KNN)
#define NEG_SLOPE 0.2f
#define BN_EPS 1e-5f
#define S_SLICES 8
#define SLICE (N_PTS/S_SLICES)   // 2048
#define FIFO_N 4

// Branchless stable insert of (pd,pj) into ascending-sorted 20-entry list.
// Strict d-compare: equal-d goes after existing -> with j-ascending arrival
// order this is exact jax.lax.top_k lex semantics. valid=false -> no-op.
__device__ __forceinline__ void insert20(float pd, int pj, bool valid,
                                         float (&Ld)[KNN], int (&Lj)[KNN])
{
    bool c[KNN];
#pragma unroll
    for (int k = 0; k < KNN; ++k) c[k] = valid && (pd < Ld[k]);
#pragma unroll
    for (int k = KNN-1; k >= 1; --k){
        Ld[k] = c[k] ? (c[k-1] ? Ld[k-1] : pd) : Ld[k];
        Lj[k] = c[k] ? (c[k-1] ? Lj[k-1] : pj) : Lj[k];
    }
    Ld[0] = c[0] ? pd : Ld[0];
    Lj[0] = c[0] ? pj : Lj[0];
}

// ============================ prep: pack (x,y,z,|p|^2) ============================
__global__ __launch_bounds__(256) void prep_kernel(const float* __restrict__ pos,
                                                   float4* __restrict__ cand4)
{
    const int j = blockIdx.x*256 + threadIdx.x;
    const float cx = pos[j*3+0], cy = pos[j*3+1], cz = pos[j*3+2];
    cand4[j] = make_float4(cx, cy, cz, cx*cx + cy*cy + cz*cz);
}

// ============================ KNN main: lane-per-query ============================
// Wave = 64 queries (one per lane) x one slice of 2048 candidates (wave-uniform
// candidate -> scalar loads). Per-lane: sorted top-20 regs + 4-deep FIFO of
// pending hits; wave drains one item/lane when any FIFO fills. No cross-lane
// data movement in the hot loop at all.
__global__ __launch_bounds__(256) void knn_main(const float4* __restrict__ cand4,
                                                float* __restrict__ d_part,
                                                int*   __restrict__ j_part)
{
    const float FINF = __builtin_inff();
    const int lane = threadIdx.x & 63;
    const int g    = blockIdx.x*4 + (threadIdx.x >> 6);  // global wave id, 0..2047
    const int s    = g >> 8;                             // slice 0..7
    const int qb   = (g & 255) * 64;                     // query base
    const int i    = qb + lane;                          // my query

    const float4 q4 = cand4[i];
    const float qx = q4.x, qy = q4.y, qz = q4.z, qsq = q4.w;

    float Ld[KNN]; int Lj[KNN];
#pragma unroll
    for (int k = 0; k < KNN; ++k){ Ld[k] = FINF; Lj[k] = 0x7FFFFFFF; }
    float Fd[FIFO_N]; int Fj[FIFO_N]; int cnt = 0;
#pragma unroll
    for (int k = 0; k < FIFO_N; ++k){ Fd[k] = FINF; Fj[k] = 0; }

    const int j0 = s*SLICE;
    for (int t = 0; t < SLICE; ++t){
        const int j = j0 + t;
        // drain before push so cnt can never exceed FIFO_N
        if (__any(cnt == FIFO_N)){
            const bool v = cnt > 0;
            float pd = Fd[0]; int pj = Fj[0];
            pd = (cnt >= 2) ? Fd[1] : pd;  pj = (cnt >= 2) ? Fj[1] : pj;
            pd = (cnt >= 3) ? Fd[2] : pd;  pj = (cnt >= 3) ? Fj[2] : pj;
            pd = (cnt >= 4) ? Fd[3] : pd;  pj = (cnt >= 4) ? Fj[3] : pj;
            cnt -= v ? 1 : 0;
            insert20(pd, pj, v, Ld, Lj);
        }
        const float4 cp = cand4[j];        // wave-uniform -> scalar load
        const float dot = qx*cp.x + qy*cp.y + qz*cp.z;
        float d = (qsq + cp.w) - 2.0f*dot; // identical expression to prior passing kernels
        if ((unsigned)(j - qb) < 64u){     // uniform branch: self only possible here
            if (lane == (j - qb)) d = FINF;
        }
        const bool c = d < Ld[KNN-1];      // my own (tight) threshold, register-local
        // FIFO shift-push: oldest migrates to highest index
        Fd[3] = c ? Fd[2] : Fd[3];  Fj[3] = c ? Fj[2] : Fj[3];
        Fd[2] = c ? Fd[1] : Fd[2];  Fj[2] = c ? Fj[1] : Fj[2];
        Fd[1] = c ? Fd[0] : Fd[1];  Fj[1] = c ? Fj[0] : Fj[1];
        Fd[0] = c ? d     : Fd[0];  Fj[0] = c ? j     : Fj[0];
        cnt += c ? 1 : 0;
    }
    // flush remaining FIFO items (<= FIFO_N rounds)
    while (__any(cnt > 0)){
        const bool v = cnt > 0;
        float pd = Fd[0]; int pj = Fj[0];
        pd = (cnt >= 2) ? Fd[1] : pd;  pj = (cnt >= 2) ? Fj[1] : pj;
        pd = (cnt >= 3) ? Fd[2] : pd;  pj = (cnt >= 3) ? Fj[2] : pj;
        pd = (cnt >= 4) ? Fd[3] : pd;  pj = (cnt >= 4) ? Fj[3] : pj;
        cnt -= v ? 1 : 0;
        insert20(pd, pj, v, Ld, Lj);
    }
    // store partials transposed: [s][k][q] -> coalesced across lanes
#pragma unroll
    for (int k = 0; k < KNN; ++k){
        d_part[(s*KNN + k)*N_PTS + i] = Ld[k];
        j_part[(s*KNN + k)*N_PTS + i] = Lj[k];
    }
}

// ============================ KNN merge: 8 sorted lists -> top-20 ============================
// Lane = query. Stream slices in ascending s (= ascending j blocks), each list
// ascending (d, stable-j) -> stable strict-d insertion stays lex-exact.
__global__ __launch_bounds__(64) void knn_merge(const float* __restrict__ d_part,
                                                const int*   __restrict__ j_part,
                                                int* __restrict__ out_idx)
{
    const float FINF = __builtin_inff();
    const int q = blockIdx.x*64 + threadIdx.x;
    float Ld[KNN]; int Lj[KNN];
#pragma unroll
    for (int k = 0; k < KNN; ++k){ Ld[k] = FINF; Lj[k] = 0x7FFFFFFF; }
    for (int s = 0; s < S_SLICES; ++s){
        for (int k = 0; k < KNN; ++k){
            const float pd = d_part[(s*KNN + k)*N_PTS + q];
            const int   pj = j_part[(s*KNN + k)*N_PTS + q];
            if (!__any(pd < Ld[KNN-1])) break;   // lists sorted: rest of slice can't enter
            insert20(pd, pj, true, Ld, Lj);
        }
    }
#pragma unroll
    for (int k = 0; k < KNN; ++k) out_idx[q*KNN + k] = Lj[k];
}

// ============================ GEMM: A = x@W_top + b, B = x@W_bot ============================
__global__ __launch_bounds__(256) void gemm_kernel(const float* __restrict__ x,
                                                   const float* __restrict__ W,
                                                   const float* __restrict__ bias,
                                                   float* __restrict__ Aout,
                                                   float* __restrict__ Bout,
                                                   float* __restrict__ stats)
{
    if (blockIdx.x == 0 && blockIdx.y == 0){
        for (int s = threadIdx.x; s < 5*COUT; s += 256) stats[s] = 0.f;
    }
    __shared__ __align__(16) float xs[64][CIN+1];
    __shared__ __align__(16) float wt[CIN][64];
    const int tid = threadIdx.x;
    const int tx = tid & 15, ty = tid >> 4;
    const int m0 = blockIdx.x*64;
    const int n0 = blockIdx.y*64;

    for (int l=tid; l<64*CIN; l+=256){
        const int row = l >> 7, k = l & (CIN-1);
        xs[row][k] = x[(m0+row)*CIN + k];
    }
    for (int l=tid; l<CIN*64; l+=256){
        const int k = l >> 6, cc = l & 63;
        const int gc = n0 + cc;
        wt[k][cc] = (gc < COUT) ? W[k*COUT + gc] : W[(CIN+k)*COUT + (gc-COUT)];
    }
    __syncthreads();

    float acc[4][4] = {};
#pragma unroll 4
    for (int k=0;k<CIN;k++){
        const float a0 = xs[ty*4+0][k];
        const float a1 = xs[ty*4+1][k];
        const float a2 = xs[ty*4+2][k];
        const float a3 = xs[ty*4+3][k];
        const float4 bv = *(const float4*)&wt[k][tx*4];
        acc[0][0] += a0*bv.x; acc[0][1] += a0*bv.y; acc[0][2] += a0*bv.z; acc[0][3] += a0*bv.w;
        acc[1][0] += a1*bv.x; acc[1][1] += a1*bv.y; acc[1][2] += a1*bv.z; acc[1][3] += a1*bv.w;
        acc[2][0] += a2*bv.x; acc[2][1] += a2*bv.y; acc[2][2] += a2*bv.z; acc[2][3] += a2*bv.w;
        acc[3][0] += a3*bv.x; acc[3][1] += a3*bv.y; acc[3][2] += a3*bv.z; acc[3][3] += a3*bv.w;
    }
    const int colg = n0 + tx*4;
    if (colg < COUT){
        const float4 bb = *(const float4*)&bias[colg];
#pragma unroll
        for (int rr=0; rr<4; ++rr){
            const float4 v = make_float4(acc[rr][0]+bb.x, acc[rr][1]+bb.y,
                                         acc[rr][2]+bb.z, acc[rr][3]+bb.w);
            *(float4*)&Aout[(m0+ty*4+rr)*COUT + colg] = v;
        }
    } else {
        const int cb = colg - COUT;
#pragma unroll
        for (int rr=0; rr<4; ++rr){
            const float4 v = make_float4(acc[rr][0], acc[rr][1], acc[rr][2], acc[rr][3]);
            *(float4*)&Bout[(m0+ty*4+rr)*COUT + cb] = v;
        }
    }
}

// ============================ Gather + stats + SEL ============================
__global__ __launch_bounds__(256) void gather_kernel(const int* __restrict__ idx,
        const float* __restrict__ A, const float* __restrict__ B,
        const float* __restrict__ gamma,
        float* __restrict__ sel, float* __restrict__ stats)
{
    __shared__ int sidx[32*KNN];
    const int c  = threadIdx.x;
    const int i0 = blockIdx.x*32;
    for (int l=c; l<32*KNN; l+=256) sidx[l] = idx[i0*KNN + l];
    __syncthreads();
    const float g = gamma[c];
    const float FINF = __builtin_inff();
    float sA=0.f, sA2=0.f, cross=0.f, sB=0.f, sB2=0.f;
    for (int ii=0; ii<32; ++ii){
        float bmax=-FINF, bmin=FINF, bsum=0.f;
#pragma unroll
        for (int k=0;k<KNN;k++){
            const int j = sidx[ii*KNN+k];
            const float v = B[j*COUT + c];
            bmax = fmaxf(bmax, v);
            bmin = fminf(bmin, v);
            bsum += v;
            sB2 += v*v;
        }
        const int i = i0 + ii;
        const float a = A[i*COUT + c];
        sA += a; sA2 += a*a; cross += a*bsum; sB += bsum;
        sel[i*COUT + c] = a + (g >= 0.f ? bmax : bmin);
    }
    atomicAdd(&stats[0*COUT+c], sA);
    atomicAdd(&stats[1*COUT+c], sA2);
    atomicAdd(&stats[2*COUT+c], cross);
    atomicAdd(&stats[3*COUT+c], sB);
    atomicAdd(&stats[4*COUT+c], sB2);
}

// ============================ Finalize stats ============================
__global__ void finalize_kernel(const float* __restrict__ stats,
                                const float* __restrict__ gamma,
                                float* __restrict__ msc)
{
    const int c = threadIdx.x;
    const float sA  = stats[0*COUT+c];
    const float sA2 = stats[1*COUT+c];
    const float cr  = stats[2*COUT+c];
    const float sB  = stats[3*COUT+c];
    const float sB2 = stats[4*COUT+c];
    const float inv_nk = 1.0f / (float)NKTOT;
    const float mean = ((float)KNN*sA + sB) * inv_nk;
    const float eh2  = ((float)KNN*sA2 + 2.f*cr + sB2) * inv_nk;
    const float var  = eh2 - mean*mean;
    msc[c]        = mean;
    msc[COUT + c] = gamma[c] * rsqrtf(var + BN_EPS);
}

// ============================ BN + LeakyReLU (in place on d_out) ============================
__global__ __launch_bounds__(256) void out_kernel(float* __restrict__ sel_out,
                                                  const float* __restrict__ msc,
                                                  const float* __restrict__ beta)
{
    const int t = blockIdx.x*256 + threadIdx.x;
    const int base = t*4;
    const int c = base & (COUT-1);
    float4 v = *(const float4*)&sel_out[base];
    const float4 m  = *(const float4*)&msc[c];
    const float4 s  = *(const float4*)&msc[COUT + c];
    const float4 bt = *(const float4*)&beta[c];
    const float y0 = (v.x - m.x)*s.x + bt.x;
    const float y1 = (v.y - m.y)*s.y + bt.y;
    const float y2 = (v.z - m.z)*s.z + bt.z;
    const float y3 = (v.w - m.w)*s.w + bt.w;
    v.x = y0 >= 0.f ? y0 : NEG_SLOPE*y0;
    v.y = y1 >= 0.f ? y1 : NEG_SLOPE*y1;
    v.z = y2 >= 0.f ? y2 : NEG_SLOPE*y2;
    v.w = y3 >= 0.f ? y3 : NEG_SLOPE*y3;
    *(float4*)&sel_out[base] = v;
}

extern "C" void kernel_launch(void* const* d_in, const int* in_sizes, int n_in,
                              void* d_out, int out_size, void* d_ws, size_t ws_size,
                              hipStream_t stream)
{
    const float* pos   = (const float*)d_in[0];
    const float* x     = (const float*)d_in[1];
    const float* W     = (const float*)d_in[2];
    const float* bias  = (const float*)d_in[3];
    const float* gamma = (const float*)d_in[4];
    const float* beta  = (const float*)d_in[5];
    float* out = (float*)d_out;
    char*  ws  = (char*)d_ws;

    // ws layout (~35.3 MB):
    // [0,2MB):   idx (1.25MB used)
    // [2MB,34MB): region X — first d_part(10.5MB)+j_part(10.5MB), then A(16MB)+B(16MB)
    //            (gemm runs AFTER merge, so A/B may overwrite the partials)
    // [34MB,..): stats (5*COUT) + msc (2*COUT)
    // then cand4 (256KB)
    int*   idx    = (int*)(ws);
    float* d_part = (float*)(ws + (2u<<20));
    int*   j_part = (int*)  (ws + (2u<<20) + (11u<<20));
    float* A      = (float*)(ws + (2u<<20));
    float* Bm     = (float*)(ws + (2u<<20) + (16u<<20));
    float* stats  = (float*)(ws + (34u<<20));
    float* msc    = stats + 5*COUT;
    float4* cand4 = (float4*)(ws + (35u<<20));

    prep_kernel    <<<dim3(64),     dim3(256), 0, stream>>>(pos, cand4);
    knn_main       <<<dim3(512),    dim3(256), 0, stream>>>(cand4, d_part, j_part);
    knn_merge      <<<dim3(256),    dim3(64),  0, stream>>>(d_part, j_part, idx);
    gemm_kernel    <<<dim3(256, 8), dim3(256), 0, stream>>>(x, W, bias, A, Bm, stats);
    gather_kernel  <<<dim3(512),    dim3(256), 0, stream>>>(idx, A, Bm, gamma, out, stats);
    finalize_kernel<<<dim3(1),      dim3(256), 0, stream>>>(stats, gamma, msc);
    out_kernel     <<<dim3(4096),   dim3(256), 0, stream>>>(out, msc, beta);
}

// Round 5
// 888.527 us; speedup vs baseline: 1.1125x; 1.1125x over previous
//
#include <hip/hip_runtime.h>

#define N_PTS 16384
#define CIN 128
#define COUT 256
#define KNN 20
#define NKTOT (N_PTS*KNN)
#define NEG_SLOPE 0.2f
#define BN_EPS 1e-5f
#define S_SLICES 8
#define SLICE (N_PTS/S_SLICES)   // 2048
#define FIFO_N 4
#define BATCH 8

// Branchless stable insert of (pd,pj) into ascending-sorted 20-entry list.
// Strict d-compare: equal-d goes after existing -> with j-ascending arrival
// order this is exact jax.lax.top_k lex semantics. valid=false -> no-op.
// Also self-guarding: pd >= Ld[19] -> no-op.
__device__ __forceinline__ void insert20(float pd, int pj, bool valid,
                                         float (&Ld)[KNN], int (&Lj)[KNN])
{
    bool c[KNN];
#pragma unroll
    for (int k = 0; k < KNN; ++k) c[k] = valid && (pd < Ld[k]);
#pragma unroll
    for (int k = KNN-1; k >= 1; --k){
        Ld[k] = c[k] ? (c[k-1] ? Ld[k-1] : pd) : Ld[k];
        Lj[k] = c[k] ? (c[k-1] ? Lj[k-1] : pj) : Lj[k];
    }
    Ld[0] = c[0] ? pd : Ld[0];
    Lj[0] = c[0] ? pj : Lj[0];
}

// Pop oldest FIFO item (index cnt-1) and insert. Identical logic to R4 (passed).
__device__ __forceinline__ void fifo_pop_insert(float (&Fd)[FIFO_N], int (&Fj)[FIFO_N],
                                                int& cnt, float (&Ld)[KNN], int (&Lj)[KNN])
{
    const bool v = cnt > 0;
    float pd = Fd[0]; int pj = Fj[0];
    pd = (cnt >= 2) ? Fd[1] : pd;  pj = (cnt >= 2) ? Fj[1] : pj;
    pd = (cnt >= 3) ? Fd[2] : pd;  pj = (cnt >= 3) ? Fj[2] : pj;
    pd = (cnt >= 4) ? Fd[3] : pd;  pj = (cnt >= 4) ? Fj[3] : pj;
    cnt -= v ? 1 : 0;
    insert20(pd, pj, v, Ld, Lj);
}

// ============================ prep: pack (x,y,z,|p|^2) ============================
__global__ __launch_bounds__(256) void prep_kernel(const float* __restrict__ pos,
                                                   float4* __restrict__ cand4)
{
    const int j = blockIdx.x*256 + threadIdx.x;
    const float cx = pos[j*3+0], cy = pos[j*3+1], cz = pos[j*3+2];
    cand4[j] = make_float4(cx, cy, cz, cx*cx + cy*cy + cz*cz);
}

// ============================ KNN main: lane-per-query, batched loads ============================
// Wave = 64 queries (one per lane) x one slice of 2048 candidates. Per batch of 8:
// all 8 cand loads issued before any use (8-deep load queue hides L2 latency),
// then 8 register-resident distance/push/drain steps. No cross-lane data
// movement; drain branch is wave-uniform and load-independent.
__global__ __launch_bounds__(256) void knn_main(const float4* __restrict__ cand4,
                                                float* __restrict__ d_part,
                                                int*   __restrict__ j_part)
{
    const float FINF = __builtin_inff();
    const int lane = threadIdx.x & 63;
    const int g    = blockIdx.x*4 + (threadIdx.x >> 6);  // global wave id, 0..2047
    const int s    = g >> 8;                             // slice 0..7
    const int qb   = (g & 255) * 64;                     // query base
    const int i    = qb + lane;                          // my query

    const float4 q4 = cand4[i];
    const float qx = q4.x, qy = q4.y, qz = q4.z, qsq = q4.w;

    float Ld[KNN]; int Lj[KNN];
#pragma unroll
    for (int k = 0; k < KNN; ++k){ Ld[k] = FINF; Lj[k] = 0x7FFFFFFF; }
    float Fd[FIFO_N]; int Fj[FIFO_N]; int cnt = 0;
#pragma unroll
    for (int k = 0; k < FIFO_N; ++k){ Fd[k] = FINF; Fj[k] = 0; }

    const int j0 = s*SLICE;
    for (int tb = 0; tb < SLICE; tb += BATCH){
        const int jb = j0 + tb;
        float4 cp[BATCH];
#pragma unroll
        for (int u = 0; u < BATCH; ++u) cp[u] = cand4[jb + u];   // issued together
#pragma unroll
        for (int u = 0; u < BATCH; ++u){
            // drain before push keeps cnt <= FIFO_N (wave-uniform branch, reg-only work)
            if (__any(cnt == FIFO_N)) fifo_pop_insert(Fd, Fj, cnt, Ld, Lj);
            const int j = jb + u;
            const float dot = qx*cp[u].x + qy*cp[u].y + qz*cp[u].z;
            float d = (qsq + cp[u].w) - 2.0f*dot;   // exact reference expression
            d = (j == i) ? FINF : d;                // branchless self-exclusion
            const bool c = d < Ld[KNN-1];           // my own tight threshold
            Fd[3] = c ? Fd[2] : Fd[3];  Fj[3] = c ? Fj[2] : Fj[3];
            Fd[2] = c ? Fd[1] : Fd[2];  Fj[2] = c ? Fj[1] : Fj[2];
            Fd[1] = c ? Fd[0] : Fd[1];  Fj[1] = c ? Fj[0] : Fj[1];
            Fd[0] = c ? d     : Fd[0];  Fj[0] = c ? j     : Fj[0];
            cnt += c ? 1 : 0;
        }
    }
    while (__any(cnt > 0)) fifo_pop_insert(Fd, Fj, cnt, Ld, Lj);

    // store partials transposed: [s][k][q] -> coalesced across lanes
#pragma unroll
    for (int k = 0; k < KNN; ++k){
        d_part[(s*KNN + k)*N_PTS + i] = Ld[k];
        j_part[(s*KNN + k)*N_PTS + i] = Lj[k];
    }
}

// ============================ KNN merge: 8 sorted lists -> top-20 ============================
// Lane = query. Slices ascending s (= ascending j blocks), each list ascending
// (d, stable-j) -> stable strict-d insertion stays lex-exact. Per-slice loads
// batched up-front (40 independent loads) to avoid a serial latency chain.
__global__ __launch_bounds__(64) void knn_merge(const float* __restrict__ d_part,
                                                const int*   __restrict__ j_part,
                                                int* __restrict__ out_idx)
{
    const float FINF = __builtin_inff();
    const int q = blockIdx.x*64 + threadIdx.x;
    float Ld[KNN]; int Lj[KNN];
#pragma unroll
    for (int k = 0; k < KNN; ++k){ Ld[k] = FINF; Lj[k] = 0x7FFFFFFF; }
    for (int s = 0; s < S_SLICES; ++s){
        float pd[KNN]; int pj[KNN];
#pragma unroll
        for (int k = 0; k < KNN; ++k){
            pd[k] = d_part[(s*KNN + k)*N_PTS + q];
            pj[k] = j_part[(s*KNN + k)*N_PTS + q];
        }
#pragma unroll
        for (int k = 0; k < KNN; ++k){
            if (!__any(pd[k] < Ld[KNN-1])) break;   // sorted: rest of slice can't enter
            insert20(pd[k], pj[k], true, Ld, Lj);
        }
    }
#pragma unroll
    for (int k = 0; k < KNN; ++k) out_idx[q*KNN + k] = Lj[k];
}

// ============================ GEMM: A = x@W_top + b, B = x@W_bot ============================
__global__ __launch_bounds__(256) void gemm_kernel(const float* __restrict__ x,
                                                   const float* __restrict__ W,
                                                   const float* __restrict__ bias,
                                                   float* __restrict__ Aout,
                                                   float* __restrict__ Bout,
                                                   float* __restrict__ stats)
{
    if (blockIdx.x == 0 && blockIdx.y == 0){
        for (int s = threadIdx.x; s < 5*COUT; s += 256) stats[s] = 0.f;
    }
    __shared__ __align__(16) float xs[64][CIN+1];
    __shared__ __align__(16) float wt[CIN][64];
    const int tid = threadIdx.x;
    const int tx = tid & 15, ty = tid >> 4;
    const int m0 = blockIdx.x*64;
    const int n0 = blockIdx.y*64;

    for (int l=tid; l<64*CIN; l+=256){
        const int row = l >> 7, k = l & (CIN-1);
        xs[row][k] = x[(m0+row)*CIN + k];
    }
    for (int l=tid; l<CIN*64; l+=256){
        const int k = l >> 6, cc = l & 63;
        const int gc = n0 + cc;
        wt[k][cc] = (gc < COUT) ? W[k*COUT + gc] : W[(CIN+k)*COUT + (gc-COUT)];
    }
    __syncthreads();

    float acc[4][4] = {};
#pragma unroll 4
    for (int k=0;k<CIN;k++){
        const float a0 = xs[ty*4+0][k];
        const float a1 = xs[ty*4+1][k];
        const float a2 = xs[ty*4+2][k];
        const float a3 = xs[ty*4+3][k];
        const float4 bv = *(const float4*)&wt[k][tx*4];
        acc[0][0] += a0*bv.x; acc[0][1] += a0*bv.y; acc[0][2] += a0*bv.z; acc[0][3] += a0*bv.w;
        acc[1][0] += a1*bv.x; acc[1][1] += a1*bv.y; acc[1][2] += a1*bv.z; acc[1][3] += a1*bv.w;
        acc[2][0] += a2*bv.x; acc[2][1] += a2*bv.y; acc[2][2] += a2*bv.z; acc[2][3] += a2*bv.w;
        acc[3][0] += a3*bv.x; acc[3][1] += a3*bv.y; acc[3][2] += a3*bv.z; acc[3][3] += a3*bv.w;
    }
    const int colg = n0 + tx*4;
    if (colg < COUT){
        const float4 bb = *(const float4*)&bias[colg];
#pragma unroll
        for (int rr=0; rr<4; ++rr){
            const float4 v = make_float4(acc[rr][0]+bb.x, acc[rr][1]+bb.y,
                                         acc[rr][2]+bb.z, acc[rr][3]+bb.w);
            *(float4*)&Aout[(m0+ty*4+rr)*COUT + colg] = v;
        }
    } else {
        const int cb = colg - COUT;
#pragma unroll
        for (int rr=0; rr<4; ++rr){
            const float4 v = make_float4(acc[rr][0], acc[rr][1], acc[rr][2], acc[rr][3]);
            *(float4*)&Bout[(m0+ty*4+rr)*COUT + cb] = v;
        }
    }
}

// ============================ Gather + stats + SEL ============================
__global__ __launch_bounds__(256) void gather_kernel(const int* __restrict__ idx,
        const float* __restrict__ A, const float* __restrict__ B,
        const float* __restrict__ gamma,
        float* __restrict__ sel, float* __restrict__ stats)
{
    __shared__ int sidx[32*KNN];
    const int c  = threadIdx.x;
    const int i0 = blockIdx.x*32;
    for (int l=c; l<32*KNN; l+=256) sidx[l] = idx[i0*KNN + l];
    __syncthreads();
    const float g = gamma[c];
    const float FINF = __builtin_inff();
    float sA=0.f, sA2=0.f, cross=0.f, sB=0.f, sB2=0.f;
    for (int ii=0; ii<32; ++ii){
        float bmax=-FINF, bmin=FINF, bsum=0.f;
#pragma unroll
        for (int k=0;k<KNN;k++){
            const int j = sidx[ii*KNN+k];
            const float v = B[j*COUT + c];
            bmax = fmaxf(bmax, v);
            bmin = fminf(bmin, v);
            bsum += v;
            sB2 += v*v;
        }
        const int i = i0 + ii;
        const float a = A[i*COUT + c];
        sA += a; sA2 += a*a; cross += a*bsum; sB += bsum;
        sel[i*COUT + c] = a + (g >= 0.f ? bmax : bmin);
    }
    atomicAdd(&stats[0*COUT+c], sA);
    atomicAdd(&stats[1*COUT+c], sA2);
    atomicAdd(&stats[2*COUT+c], cross);
    atomicAdd(&stats[3*COUT+c], sB);
    atomicAdd(&stats[4*COUT+c], sB2);
}

// ============================ Finalize stats ============================
__global__ void finalize_kernel(const float* __restrict__ stats,
                                const float* __restrict__ gamma,
                                float* __restrict__ msc)
{
    const int c = threadIdx.x;
    const float sA  = stats[0*COUT+c];
    const float sA2 = stats[1*COUT+c];
    const float cr  = stats[2*COUT+c];
    const float sB  = stats[3*COUT+c];
    const float sB2 = stats[4*COUT+c];
    const float inv_nk = 1.0f / (float)NKTOT;
    const float mean = ((float)KNN*sA + sB) * inv_nk;
    const float eh2  = ((float)KNN*sA2 + 2.f*cr + sB2) * inv_nk;
    const float var  = eh2 - mean*mean;
    msc[c]        = mean;
    msc[COUT + c] = gamma[c] * rsqrtf(var + BN_EPS);
}

// ============================ BN + LeakyReLU (in place on d_out) ============================
__global__ __launch_bounds__(256) void out_kernel(float* __restrict__ sel_out,
                                                  const float* __restrict__ msc,
                                                  const float* __restrict__ beta)
{
    const int t = blockIdx.x*256 + threadIdx.x;
    const int base = t*4;
    const int c = base & (COUT-1);
    float4 v = *(const float4*)&sel_out[base];
    const float4 m  = *(const float4*)&msc[c];
    const float4 s  = *(const float4*)&msc[COUT + c];
    const float4 bt = *(const float4*)&beta[c];
    const float y0 = (v.x - m.x)*s.x + bt.x;
    const float y1 = (v.y - m.y)*s.y + bt.y;
    const float y2 = (v.z - m.z)*s.z + bt.z;
    const float y3 = (v.w - m.w)*s.w + bt.w;
    v.x = y0 >= 0.f ? y0 : NEG_SLOPE*y0;
    v.y = y1 >= 0.f ? y1 : NEG_SLOPE*y1;
    v.z = y2 >= 0.f ? y2 : NEG_SLOPE*y2;
    v.w = y3 >= 0.f ? y3 : NEG_SLOPE*y3;
    *(float4*)&sel_out[base] = v;
}

extern "C" void kernel_launch(void* const* d_in, const int* in_sizes, int n_in,
                              void* d_out, int out_size, void* d_ws, size_t ws_size,
                              hipStream_t stream)
{
    const float* pos   = (const float*)d_in[0];
    const float* x     = (const float*)d_in[1];
    const float* W     = (const float*)d_in[2];
    const float* bias  = (const float*)d_in[3];
    const float* gamma = (const float*)d_in[4];
    const float* beta  = (const float*)d_in[5];
    float* out = (float*)d_out;
    char*  ws  = (char*)d_ws;

    // ws layout (~35.3 MB):
    // [0,2MB):    idx (1.25MB used)
    // [2MB,34MB): region X — first d_part(10.5MB)+j_part(10.5MB), then A(16MB)+B(16MB)
    //             (gemm runs AFTER merge, so A/B may overwrite the partials)
    // [34MB,..):  stats (5*COUT) + msc (2*COUT)
    // [35MB,..):  cand4 (256KB)
    int*   idx    = (int*)(ws);
    float* d_part = (float*)(ws + (2u<<20));
    int*   j_part = (int*)  (ws + (2u<<20) + (11u<<20));
    float* A      = (float*)(ws + (2u<<20));
    float* Bm     = (float*)(ws + (2u<<20) + (16u<<20));
    float* stats  = (float*)(ws + (34u<<20));
    float* msc    = stats + 5*COUT;
    float4* cand4 = (float4*)(ws + (35u<<20));

    prep_kernel    <<<dim3(64),     dim3(256), 0, stream>>>(pos, cand4);
    knn_main       <<<dim3(512),    dim3(256), 0, stream>>>(cand4, d_part, j_part);
    knn_merge      <<<dim3(256),    dim3(64),  0, stream>>>(d_part, j_part, idx);
    gemm_kernel    <<<dim3(256, 8), dim3(256), 0, stream>>>(x, W, bias, A, Bm, stats);
    gather_kernel  <<<dim3(512),    dim3(256), 0, stream>>>(idx, A, Bm, gamma, out, stats);
    finalize_kernel<<<dim3(1),      dim3(256), 0, stream>>>(stats, gamma, msc);
    out_kernel     <<<dim3(4096),   dim3(256), 0, stream>>>(out, msc, beta);
}

// Round 6
// 885.227 us; speedup vs baseline: 1.1166x; 1.0037x over previous
//
#include <hip/hip_runtime.h>

#define N_PTS 16384
#define CIN 128
#define COUT 256
#define KNN 20
#define NKTOT (N_PTS*KNN)
#define NEG_SLOPE 0.2f
#define BN_EPS 1e-5f
#define S_SLICES 8
#define SLICE (N_PTS/S_SLICES)   // 2048
#define FIFO_N 4
#define BATCH 8

// Branchless stable insert of (pd,pj) into ascending-sorted 20-entry list.
// Strict d-compare: equal-d goes after existing -> with j-ascending arrival
// order this is exact jax.lax.top_k lex semantics. valid=false -> no-op.
__device__ __forceinline__ void insert20(float pd, int pj, bool valid,
                                         float (&Ld)[KNN], int (&Lj)[KNN])
{
    bool c[KNN];
#pragma unroll
    for (int k = 0; k < KNN; ++k) c[k] = valid && (pd < Ld[k]);
#pragma unroll
    for (int k = KNN-1; k >= 1; --k){
        Ld[k] = c[k] ? (c[k-1] ? Ld[k-1] : pd) : Ld[k];
        Lj[k] = c[k] ? (c[k-1] ? Lj[k-1] : pj) : Lj[k];
    }
    Ld[0] = c[0] ? pd : Ld[0];
    Lj[0] = c[0] ? pj : Lj[0];
}

// Pop oldest FIFO item (index cnt-1) and insert. Identical logic to R4/R5 (passed).
__device__ __forceinline__ void fifo_pop_insert(float (&Fd)[FIFO_N], int (&Fj)[FIFO_N],
                                                int& cnt, float (&Ld)[KNN], int (&Lj)[KNN])
{
    const bool v = cnt > 0;
    float pd = Fd[0]; int pj = Fj[0];
    pd = (cnt >= 2) ? Fd[1] : pd;  pj = (cnt >= 2) ? Fj[1] : pj;
    pd = (cnt >= 3) ? Fd[2] : pd;  pj = (cnt >= 3) ? Fj[2] : pj;
    pd = (cnt >= 4) ? Fd[3] : pd;  pj = (cnt >= 4) ? Fj[3] : pj;
    cnt -= v ? 1 : 0;
    insert20(pd, pj, v, Ld, Lj);
}

// ============================ prep: pack (x,y,z,|p|^2) ============================
__global__ __launch_bounds__(256) void prep_kernel(const float* __restrict__ pos,
                                                   float4* __restrict__ cand4)
{
    const int j = blockIdx.x*256 + threadIdx.x;
    const float cx = pos[j*3+0], cy = pos[j*3+1], cz = pos[j*3+2];
    cand4[j] = make_float4(cx, cy, cz, cx*cx + cy*cy + cz*cz);
}

// ============================ KNN main: lane-per-query, batched loads ============================
// Wave = 64 queries (one per lane) x one slice of 2048 candidates. Per batch of 8:
// all 8 cand loads issued before any use, then 8 register-resident steps.
// __launch_bounds__(256,1): ~110 live VGPRs (Ld/Lj/FIFO/cp batch) MUST stay in
// registers — R5's default budget (64) spilled the hot-loop state to scratch
// (FETCH_SIZE 1.27 GB of spill traffic, threshold check loading from scratch
// every step). Grid gives only 2 waves/SIMD anyway, so high VGPR costs nothing.
__global__ __launch_bounds__(256, 1) void knn_main(const float4* __restrict__ cand4,
                                                   float* __restrict__ d_part,
                                                   int*   __restrict__ j_part)
{
    const float FINF = __builtin_inff();
    const int lane = threadIdx.x & 63;
    const int g    = blockIdx.x*4 + (threadIdx.x >> 6);  // global wave id, 0..2047
    const int s    = g >> 8;                             // slice 0..7
    const int qb   = (g & 255) * 64;                     // query base
    const int i    = qb + lane;                          // my query

    const float4 q4 = cand4[i];
    const float qx = q4.x, qy = q4.y, qz = q4.z, qsq = q4.w;

    float Ld[KNN]; int Lj[KNN];
#pragma unroll
    for (int k = 0; k < KNN; ++k){ Ld[k] = FINF; Lj[k] = 0x7FFFFFFF; }
    float Fd[FIFO_N]; int Fj[FIFO_N]; int cnt = 0;
#pragma unroll
    for (int k = 0; k < FIFO_N; ++k){ Fd[k] = FINF; Fj[k] = 0; }

    const int j0 = s*SLICE;
    for (int tb = 0; tb < SLICE; tb += BATCH){
        const int jb = j0 + tb;
        float4 cp[BATCH];
#pragma unroll
        for (int u = 0; u < BATCH; ++u) cp[u] = cand4[jb + u];   // issued together
#pragma unroll
        for (int u = 0; u < BATCH; ++u){
            // drain before push keeps cnt <= FIFO_N (wave-uniform branch, reg-only work)
            if (__any(cnt == FIFO_N)) fifo_pop_insert(Fd, Fj, cnt, Ld, Lj);
            const int j = jb + u;
            const float dot = qx*cp[u].x + qy*cp[u].y + qz*cp[u].z;
            float d = (qsq + cp[u].w) - 2.0f*dot;   // exact reference expression
            d = (j == i) ? FINF : d;                // branchless self-exclusion
            const bool c = d < Ld[KNN-1];           // my own tight threshold
            Fd[3] = c ? Fd[2] : Fd[3];  Fj[3] = c ? Fj[2] : Fj[3];
            Fd[2] = c ? Fd[1] : Fd[2];  Fj[2] = c ? Fj[1] : Fj[2];
            Fd[1] = c ? Fd[0] : Fd[1];  Fj[1] = c ? Fj[0] : Fj[1];
            Fd[0] = c ? d     : Fd[0];  Fj[0] = c ? j     : Fj[0];
            cnt += c ? 1 : 0;
        }
    }
    while (__any(cnt > 0)) fifo_pop_insert(Fd, Fj, cnt, Ld, Lj);

    // store partials transposed: [s][k][q] -> coalesced across lanes
#pragma unroll
    for (int k = 0; k < KNN; ++k){
        d_part[(s*KNN + k)*N_PTS + i] = Ld[k];
        j_part[(s*KNN + k)*N_PTS + i] = Lj[k];
    }
}

// ============================ KNN merge: 8 sorted lists -> top-20 ============================
// Lane = query. Slices ascending s (= ascending j blocks), each list ascending
// (d, stable-j) -> stable strict-d insertion stays lex-exact. Per-slice loads
// batched up-front. __launch_bounds__(64,1): ~90 live VGPRs, no spills.
__global__ __launch_bounds__(64, 1) void knn_merge(const float* __restrict__ d_part,
                                                   const int*   __restrict__ j_part,
                                                   int* __restrict__ out_idx)
{
    const float FINF = __builtin_inff();
    const int q = blockIdx.x*64 + threadIdx.x;
    float Ld[KNN]; int Lj[KNN];
#pragma unroll
    for (int k = 0; k < KNN; ++k){ Ld[k] = FINF; Lj[k] = 0x7FFFFFFF; }
    for (int s = 0; s < S_SLICES; ++s){
        float pd[KNN]; int pj[KNN];
#pragma unroll
        for (int k = 0; k < KNN; ++k){
            pd[k] = d_part[(s*KNN + k)*N_PTS + q];
            pj[k] = j_part[(s*KNN + k)*N_PTS + q];
        }
#pragma unroll
        for (int k = 0; k < KNN; ++k){
            if (!__any(pd[k] < Ld[KNN-1])) break;   // sorted: rest of slice can't enter
            insert20(pd[k], pj[k], true, Ld, Lj);
        }
    }
#pragma unroll
    for (int k = 0; k < KNN; ++k) out_idx[q*KNN + k] = Lj[k];
}

// ============================ GEMM: A = x@W_top + b, B = x@W_bot ============================
__global__ __launch_bounds__(256) void gemm_kernel(const float* __restrict__ x,
                                                   const float* __restrict__ W,
                                                   const float* __restrict__ bias,
                                                   float* __restrict__ Aout,
                                                   float* __restrict__ Bout,
                                                   float* __restrict__ stats)
{
    if (blockIdx.x == 0 && blockIdx.y == 0){
        for (int s = threadIdx.x; s < 5*COUT; s += 256) stats[s] = 0.f;
    }
    __shared__ __align__(16) float xs[64][CIN+1];
    __shared__ __align__(16) float wt[CIN][64];
    const int tid = threadIdx.x;
    const int tx = tid & 15, ty = tid >> 4;
    const int m0 = blockIdx.x*64;
    const int n0 = blockIdx.y*64;

    for (int l=tid; l<64*CIN; l+=256){
        const int row = l >> 7, k = l & (CIN-1);
        xs[row][k] = x[(m0+row)*CIN + k];
    }
    for (int l=tid; l<CIN*64; l+=256){
        const int k = l >> 6, cc = l & 63;
        const int gc = n0 + cc;
        wt[k][cc] = (gc < COUT) ? W[k*COUT + gc] : W[(CIN+k)*COUT + (gc-COUT)];
    }
    __syncthreads();

    float acc[4][4] = {};
#pragma unroll 4
    for (int k=0;k<CIN;k++){
        const float a0 = xs[ty*4+0][k];
        const float a1 = xs[ty*4+1][k];
        const float a2 = xs[ty*4+2][k];
        const float a3 = xs[ty*4+3][k];
        const float4 bv = *(const float4*)&wt[k][tx*4];
        acc[0][0] += a0*bv.x; acc[0][1] += a0*bv.y; acc[0][2] += a0*bv.z; acc[0][3] += a0*bv.w;
        acc[1][0] += a1*bv.x; acc[1][1] += a1*bv.y; acc[1][2] += a1*bv.z; acc[1][3] += a1*bv.w;
        acc[2][0] += a2*bv.x; acc[2][1] += a2*bv.y; acc[2][2] += a2*bv.z; acc[2][3] += a2*bv.w;
        acc[3][0] += a3*bv.x; acc[3][1] += a3*bv.y; acc[3][2] += a3*bv.z; acc[3][3] += a3*bv.w;
    }
    const int colg = n0 + tx*4;
    if (colg < COUT){
        const float4 bb = *(const float4*)&bias[colg];
#pragma unroll
        for (int rr=0; rr<4; ++rr){
            const float4 v = make_float4(acc[rr][0]+bb.x, acc[rr][1]+bb.y,
                                         acc[rr][2]+bb.z, acc[rr][3]+bb.w);
            *(float4*)&Aout[(m0+ty*4+rr)*COUT + colg] = v;
        }
    } else {
        const int cb = colg - COUT;
#pragma unroll
        for (int rr=0; rr<4; ++rr){
            const float4 v = make_float4(acc[rr][0], acc[rr][1], acc[rr][2], acc[rr][3]);
            *(float4*)&Bout[(m0+ty*4+rr)*COUT + cb] = v;
        }
    }
}

// ============================ Gather + stats + SEL ============================
__global__ __launch_bounds__(256) void gather_kernel(const int* __restrict__ idx,
        const float* __restrict__ A, const float* __restrict__ B,
        const float* __restrict__ gamma,
        float* __restrict__ sel, float* __restrict__ stats)
{
    __shared__ int sidx[32*KNN];
    const int c  = threadIdx.x;
    const int i0 = blockIdx.x*32;
    for (int l=c; l<32*KNN; l+=256) sidx[l] = idx[i0*KNN + l];
    __syncthreads();
    const float g = gamma[c];
    const float FINF = __builtin_inff();
    float sA=0.f, sA2=0.f, cross=0.f, sB=0.f, sB2=0.f;
    for (int ii=0; ii<32; ++ii){
        float bmax=-FINF, bmin=FINF, bsum=0.f;
#pragma unroll
        for (int k=0;k<KNN;k++){
            const int j = sidx[ii*KNN+k];
            const float v = B[j*COUT + c];
            bmax = fmaxf(bmax, v);
            bmin = fminf(bmin, v);
            bsum += v;
            sB2 += v*v;
        }
        const int i = i0 + ii;
        const float a = A[i*COUT + c];
        sA += a; sA2 += a*a; cross += a*bsum; sB += bsum;
        sel[i*COUT + c] = a + (g >= 0.f ? bmax : bmin);
    }
    atomicAdd(&stats[0*COUT+c], sA);
    atomicAdd(&stats[1*COUT+c], sA2);
    atomicAdd(&stats[2*COUT+c], cross);
    atomicAdd(&stats[3*COUT+c], sB);
    atomicAdd(&stats[4*COUT+c], sB2);
}

// ============================ Finalize stats ============================
__global__ void finalize_kernel(const float* __restrict__ stats,
                                const float* __restrict__ gamma,
                                float* __restrict__ msc)
{
    const int c = threadIdx.x;
    const float sA  = stats[0*COUT+c];
    const float sA2 = stats[1*COUT+c];
    const float cr  = stats[2*COUT+c];
    const float sB  = stats[3*COUT+c];
    const float sB2 = stats[4*COUT+c];
    const float inv_nk = 1.0f / (float)NKTOT;
    const float mean = ((float)KNN*sA + sB) * inv_nk;
    const float eh2  = ((float)KNN*sA2 + 2.f*cr + sB2) * inv_nk;
    const float var  = eh2 - mean*mean;
    msc[c]        = mean;
    msc[COUT + c] = gamma[c] * rsqrtf(var + BN_EPS);
}

// ============================ BN + LeakyReLU (in place on d_out) ============================
__global__ __launch_bounds__(256) void out_kernel(float* __restrict__ sel_out,
                                                  const float* __restrict__ msc,
                                                  const float* __restrict__ beta)
{
    const int t = blockIdx.x*256 + threadIdx.x;
    const int base = t*4;
    const int c = base & (COUT-1);
    float4 v = *(const float4*)&sel_out[base];
    const float4 m  = *(const float4*)&msc[c];
    const float4 s  = *(const float4*)&msc[COUT + c];
    const float4 bt = *(const float4*)&beta[c];
    const float y0 = (v.x - m.x)*s.x + bt.x;
    const float y1 = (v.y - m.y)*s.y + bt.y;
    const float y2 = (v.z - m.z)*s.z + bt.z;
    const float y3 = (v.w - m.w)*s.w + bt.w;
    v.x = y0 >= 0.f ? y0 : NEG_SLOPE*y0;
    v.y = y1 >= 0.f ? y1 : NEG_SLOPE*y1;
    v.z = y2 >= 0.f ? y2 : NEG_SLOPE*y2;
    v.w = y3 >= 0.f ? y3 : NEG_SLOPE*y3;
    *(float4*)&sel_out[base] = v;
}

extern "C" void kernel_launch(void* const* d_in, const int* in_sizes, int n_in,
                              void* d_out, int out_size, void* d_ws, size_t ws_size,
                              hipStream_t stream)
{
    const float* pos   = (const float*)d_in[0];
    const float* x     = (const float*)d_in[1];
    const float* W     = (const float*)d_in[2];
    const float* bias  = (const float*)d_in[3];
    const float* gamma = (const float*)d_in[4];
    const float* beta  = (const float*)d_in[5];
    float* out = (float*)d_out;
    char*  ws  = (char*)d_ws;

    // ws layout (~35.3 MB):
    // [0,2MB):    idx (1.25MB used)
    // [2MB,34MB): region X — first d_part(10.5MB)+j_part(10.5MB), then A(16MB)+B(16MB)
    //             (gemm runs AFTER merge, so A/B may overwrite the partials)
    // [34MB,..):  stats (5*COUT) + msc (2*COUT)
    // [35MB,..):  cand4 (256KB)
    int*   idx    = (int*)(ws);
    float* d_part = (float*)(ws + (2u<<20));
    int*   j_part = (int*)  (ws + (2u<<20) + (11u<<20));
    float* A      = (float*)(ws + (2u<<20));
    float* Bm     = (float*)(ws + (2u<<20) + (16u<<20));
    float* stats  = (float*)(ws + (34u<<20));
    float* msc    = stats + 5*COUT;
    float4* cand4 = (float4*)(ws + (35u<<20));

    prep_kernel    <<<dim3(64),     dim3(256), 0, stream>>>(pos, cand4);
    knn_main       <<<dim3(512),    dim3(256), 0, stream>>>(cand4, d_part, j_part);
    knn_merge      <<<dim3(256),    dim3(64),  0, stream>>>(d_part, j_part, idx);
    gemm_kernel    <<<dim3(256, 8), dim3(256), 0, stream>>>(x, W, bias, A, Bm, stats);
    gather_kernel  <<<dim3(512),    dim3(256), 0, stream>>>(idx, A, Bm, gamma, out, stats);
    finalize_kernel<<<dim3(1),      dim3(256), 0, stream>>>(stats, gamma, msc);
    out_kernel     <<<dim3(4096),   dim3(256), 0, stream>>>(out, msc, beta);
}

// Round 7
// 834.599 us; speedup vs baseline: 1.1844x; 1.0607x over previous
//
#include <hip/hip_runtime.h>

#define N_PTS 16384
#define CIN 128
#define COUT 256
#define KNN 20
#define NKTOT (N_PTS*KNN)
#define NEG_SLOPE 0.2f
#define BN_EPS 1e-5f
#define S_SLICES 8
#define SLICE (N_PTS/S_SLICES)   // 2048
#define FIFO_N 4
#define BATCH 8

// Branchless stable insert of (pd,pj) into ascending-sorted 20-entry list.
// Strict d-compare: equal-d goes after existing -> with j-ascending arrival
// order this is exact jax.lax.top_k lex semantics. valid=false -> no-op.
__device__ __forceinline__ void insert20(float pd, int pj, bool valid,
                                         float (&Ld)[KNN], int (&Lj)[KNN])
{
    bool c[KNN];
#pragma unroll
    for (int k = 0; k < KNN; ++k) c[k] = valid && (pd < Ld[k]);
#pragma unroll
    for (int k = KNN-1; k >= 1; --k){
        Ld[k] = c[k] ? (c[k-1] ? Ld[k-1] : pd) : Ld[k];
        Lj[k] = c[k] ? (c[k-1] ? Lj[k-1] : pj) : Lj[k];
    }
    Ld[0] = c[0] ? pd : Ld[0];
    Lj[0] = c[0] ? pj : Lj[0];
}

// Pop oldest FIFO item and insert. Identical logic to R4-R6 (passed).
__device__ __forceinline__ void fifo_pop_insert(float (&Fd)[FIFO_N], int (&Fj)[FIFO_N],
                                                int& cnt, float (&Ld)[KNN], int (&Lj)[KNN])
{
    const bool v = cnt > 0;
    float pd = Fd[0]; int pj = Fj[0];
    pd = (cnt >= 2) ? Fd[1] : pd;  pj = (cnt >= 2) ? Fj[1] : pj;
    pd = (cnt >= 3) ? Fd[2] : pd;  pj = (cnt >= 3) ? Fj[2] : pj;
    pd = (cnt >= 4) ? Fd[3] : pd;  pj = (cnt >= 4) ? Fj[3] : pj;
    cnt -= v ? 1 : 0;
    insert20(pd, pj, v, Ld, Lj);
}

// ============================ prep: pack (x,y,z,|p|^2) + tau=INF ============================
__global__ __launch_bounds__(256) void prep_kernel(const float* __restrict__ pos,
                                                   float4* __restrict__ cand4,
                                                   float* __restrict__ tau)
{
    const int j = blockIdx.x*256 + threadIdx.x;
    const float cx = pos[j*3+0], cy = pos[j*3+1], cz = pos[j*3+2];
    cand4[j] = make_float4(cx, cy, cz, cx*cx + cy*cy + cz*cz);
    tau[j] = __builtin_inff();   // ws is 0xAA-poisoned (negative float) -> must init
}

// ============================ KNN main: lane-per-query + shared threshold ============================
// Wave = 64 queries (one per lane) x one slice of 2048 candidates.
// NEW vs R6: global per-query bound tau[i] (any wave's current 20th is an upper
// bound on the query's global 20th; subset-20th >= superset-20th). Push filter
// lim = min(tau_checkpoint, own Ld[19]) keeps every true global-top-20 member
// (each is strictly below every such bound when scanned) -> merge stays exact.
// This collapses insert work from ~900/query (8 independent slice fills) to
// ~154/query + warmup: the R6 profile showed ~74 VALU inst/step (drain-dominated);
// now drains are rare after ~64 steps.
__global__ __launch_bounds__(256, 1) void knn_main(const float4* __restrict__ cand4,
                                                   float* __restrict__ tau,
                                                   float* __restrict__ d_part,
                                                   int*   __restrict__ j_part)
{
    const float FINF = __builtin_inff();
    const int lane = threadIdx.x & 63;
    const int g    = blockIdx.x*4 + (threadIdx.x >> 6);  // global wave id, 0..2047
    const int s    = g >> 8;                             // slice 0..7
    const int qb   = (g & 255) * 64;                     // query base
    const int i    = qb + lane;                          // my query

    const float4 q4 = cand4[i];
    const float qx = q4.x, qy = q4.y, qz = q4.z, qsq = q4.w;

    float Ld[KNN]; int Lj[KNN];
#pragma unroll
    for (int k = 0; k < KNN; ++k){ Ld[k] = FINF; Lj[k] = 0x7FFFFFFF; }
    float Fd[FIFO_N]; int Fj[FIFO_N]; int cnt = 0;
#pragma unroll
    for (int k = 0; k < FIFO_N; ++k){ Fd[k] = FINF; Fj[k] = 0; }

    float thr = FINF;            // cross-wave bound from last checkpoint
    const int j0 = s*SLICE;
    for (int tb = 0; tb < SLICE; tb += BATCH){
        if ((tb & 31) == 0 && tb){            // checkpoint every 32 candidates
            const float tv = *(volatile float*)&tau[i];   // stale = looser = safe
            const float mine = Ld[KNN-1];
            if (mine < tv) atomicMin((int*)&tau[i], __float_as_int(mine));
            thr = fminf(tv, mine);
        }
        const int jb = j0 + tb;
        float4 cp[BATCH];
#pragma unroll
        for (int u = 0; u < BATCH; ++u) cp[u] = cand4[jb + u];   // issued together
#pragma unroll
        for (int u = 0; u < BATCH; ++u){
            // drain before push keeps cnt <= FIFO_N (wave-uniform branch, reg-only work)
            if (__any(cnt == FIFO_N)) fifo_pop_insert(Fd, Fj, cnt, Ld, Lj);
            const int j = jb + u;
            const float dot = qx*cp[u].x + qy*cp[u].y + qz*cp[u].z;
            float d = (qsq + cp[u].w) - 2.0f*dot;   // exact reference expression
            d = (j == i) ? FINF : d;                // branchless self-exclusion
            const float lim = fminf(thr, Ld[KNN-1]);
            const bool c = d < lim;
            Fd[3] = c ? Fd[2] : Fd[3];  Fj[3] = c ? Fj[2] : Fj[3];
            Fd[2] = c ? Fd[1] : Fd[2];  Fj[2] = c ? Fj[1] : Fj[2];
            Fd[1] = c ? Fd[0] : Fd[1];  Fj[1] = c ? Fj[0] : Fj[1];
            Fd[0] = c ? d     : Fd[0];  Fj[0] = c ? j     : Fj[0];
            cnt += c ? 1 : 0;
        }
    }
    while (__any(cnt > 0)) fifo_pop_insert(Fd, Fj, cnt, Ld, Lj);

    // final publish (helps waves still scanning)
    {
        const float mine = Ld[KNN-1];
        if (mine < thr) atomicMin((int*)&tau[i], __float_as_int(mine));
    }
    // store partials transposed: [s][k][q] -> coalesced across lanes
#pragma unroll
    for (int k = 0; k < KNN; ++k){
        d_part[(s*KNN + k)*N_PTS + i] = Ld[k];
        j_part[(s*KNN + k)*N_PTS + i] = Lj[k];
    }
}

// ============================ KNN merge: 8 sorted lists -> top-20 ============================
// Lane = query. Slices ascending s (= ascending j blocks), each list ascending
// (d, stable-j) -> stable strict-d insertion stays lex-exact. Pruned slice
// lists may be mostly sentinels; the __any-break skips them fast.
__global__ __launch_bounds__(64, 1) void knn_merge(const float* __restrict__ d_part,
                                                   const int*   __restrict__ j_part,
                                                   int* __restrict__ out_idx)
{
    const float FINF = __builtin_inff();
    const int q = blockIdx.x*64 + threadIdx.x;
    float Ld[KNN]; int Lj[KNN];
#pragma unroll
    for (int k = 0; k < KNN; ++k){ Ld[k] = FINF; Lj[k] = 0x7FFFFFFF; }
    for (int s = 0; s < S_SLICES; ++s){
        float pd[KNN]; int pj[KNN];
#pragma unroll
        for (int k = 0; k < KNN; ++k){
            pd[k] = d_part[(s*KNN + k)*N_PTS + q];
            pj[k] = j_part[(s*KNN + k)*N_PTS + q];
        }
#pragma unroll
        for (int k = 0; k < KNN; ++k){
            if (!__any(pd[k] < Ld[KNN-1])) break;   // sorted: rest of slice can't enter
            insert20(pd[k], pj[k], true, Ld, Lj);
        }
    }
#pragma unroll
    for (int k = 0; k < KNN; ++k) out_idx[q*KNN + k] = Lj[k];
}

// ============================ GEMM: A = x@W_top + b, B = x@W_bot ============================
__global__ __launch_bounds__(256) void gemm_kernel(const float* __restrict__ x,
                                                   const float* __restrict__ W,
                                                   const float* __restrict__ bias,
                                                   float* __restrict__ Aout,
                                                   float* __restrict__ Bout,
                                                   float* __restrict__ stats)
{
    if (blockIdx.x == 0 && blockIdx.y == 0){
        for (int s = threadIdx.x; s < 5*COUT; s += 256) stats[s] = 0.f;
    }
    __shared__ __align__(16) float xs[64][CIN+1];
    __shared__ __align__(16) float wt[CIN][64];
    const int tid = threadIdx.x;
    const int tx = tid & 15, ty = tid >> 4;
    const int m0 = blockIdx.x*64;
    const int n0 = blockIdx.y*64;

    for (int l=tid; l<64*CIN; l+=256){
        const int row = l >> 7, k = l & (CIN-1);
        xs[row][k] = x[(m0+row)*CIN + k];
    }
    for (int l=tid; l<CIN*64; l+=256){
        const int k = l >> 6, cc = l & 63;
        const int gc = n0 + cc;
        wt[k][cc] = (gc < COUT) ? W[k*COUT + gc] : W[(CIN+k)*COUT + (gc-COUT)];
    }
    __syncthreads();

    float acc[4][4] = {};
#pragma unroll 4
    for (int k=0;k<CIN;k++){
        const float a0 = xs[ty*4+0][k];
        const float a1 = xs[ty*4+1][k];
        const float a2 = xs[ty*4+2][k];
        const float a3 = xs[ty*4+3][k];
        const float4 bv = *(const float4*)&wt[k][tx*4];
        acc[0][0] += a0*bv.x; acc[0][1] += a0*bv.y; acc[0][2] += a0*bv.z; acc[0][3] += a0*bv.w;
        acc[1][0] += a1*bv.x; acc[1][1] += a1*bv.y; acc[1][2] += a1*bv.z; acc[1][3] += a1*bv.w;
        acc[2][0] += a2*bv.x; acc[2][1] += a2*bv.y; acc[2][2] += a2*bv.z; acc[2][3] += a2*bv.w;
        acc[3][0] += a3*bv.x; acc[3][1] += a3*bv.y; acc[3][2] += a3*bv.z; acc[3][3] += a3*bv.w;
    }
    const int colg = n0 + tx*4;
    if (colg < COUT){
        const float4 bb = *(const float4*)&bias[colg];
#pragma unroll
        for (int rr=0; rr<4; ++rr){
            const float4 v = make_float4(acc[rr][0]+bb.x, acc[rr][1]+bb.y,
                                         acc[rr][2]+bb.z, acc[rr][3]+bb.w);
            *(float4*)&Aout[(m0+ty*4+rr)*COUT + colg] = v;
        }
    } else {
        const int cb = colg - COUT;
#pragma unroll
        for (int rr=0; rr<4; ++rr){
            const float4 v = make_float4(acc[rr][0], acc[rr][1], acc[rr][2], acc[rr][3]);
            *(float4*)&Bout[(m0+ty*4+rr)*COUT + cb] = v;
        }
    }
}

// ============================ Gather + stats + SEL ============================
__global__ __launch_bounds__(256) void gather_kernel(const int* __restrict__ idx,
        const float* __restrict__ A, const float* __restrict__ B,
        const float* __restrict__ gamma,
        float* __restrict__ sel, float* __restrict__ stats)
{
    __shared__ int sidx[32*KNN];
    const int c  = threadIdx.x;
    const int i0 = blockIdx.x*32;
    for (int l=c; l<32*KNN; l+=256) sidx[l] = idx[i0*KNN + l];
    __syncthreads();
    const float g = gamma[c];
    const float FINF = __builtin_inff();
    float sA=0.f, sA2=0.f, cross=0.f, sB=0.f, sB2=0.f;
    for (int ii=0; ii<32; ++ii){
        float bmax=-FINF, bmin=FINF, bsum=0.f;
#pragma unroll
        for (int k=0;k<KNN;k++){
            const int j = sidx[ii*KNN+k];
            const float v = B[j*COUT + c];
            bmax = fmaxf(bmax, v);
            bmin = fminf(bmin, v);
            bsum += v;
            sB2 += v*v;
        }
        const int i = i0 + ii;
        const float a = A[i*COUT + c];
        sA += a; sA2 += a*a; cross += a*bsum; sB += bsum;
        sel[i*COUT + c] = a + (g >= 0.f ? bmax : bmin);
    }
    atomicAdd(&stats[0*COUT+c], sA);
    atomicAdd(&stats[1*COUT+c], sA2);
    atomicAdd(&stats[2*COUT+c], cross);
    atomicAdd(&stats[3*COUT+c], sB);
    atomicAdd(&stats[4*COUT+c], sB2);
}

// ============================ Finalize stats ============================
__global__ void finalize_kernel(const float* __restrict__ stats,
                                const float* __restrict__ gamma,
                                float* __restrict__ msc)
{
    const int c = threadIdx.x;
    const float sA  = stats[0*COUT+c];
    const float sA2 = stats[1*COUT+c];
    const float cr  = stats[2*COUT+c];
    const float sB  = stats[3*COUT+c];
    const float sB2 = stats[4*COUT+c];
    const float inv_nk = 1.0f / (float)NKTOT;
    const float mean = ((float)KNN*sA + sB) * inv_nk;
    const float eh2  = ((float)KNN*sA2 + 2.f*cr + sB2) * inv_nk;
    const float var  = eh2 - mean*mean;
    msc[c]        = mean;
    msc[COUT + c] = gamma[c] * rsqrtf(var + BN_EPS);
}

// ============================ BN + LeakyReLU (in place on d_out) ============================
__global__ __launch_bounds__(256) void out_kernel(float* __restrict__ sel_out,
                                                  const float* __restrict__ msc,
                                                  const float* __restrict__ beta)
{
    const int t = blockIdx.x*256 + threadIdx.x;
    const int base = t*4;
    const int c = base & (COUT-1);
    float4 v = *(const float4*)&sel_out[base];
    const float4 m  = *(const float4*)&msc[c];
    const float4 s  = *(const float4*)&msc[COUT + c];
    const float4 bt = *(const float4*)&beta[c];
    const float y0 = (v.x - m.x)*s.x + bt.x;
    const float y1 = (v.y - m.y)*s.y + bt.y;
    const float y2 = (v.z - m.z)*s.z + bt.z;
    const float y3 = (v.w - m.w)*s.w + bt.w;
    v.x = y0 >= 0.f ? y0 : NEG_SLOPE*y0;
    v.y = y1 >= 0.f ? y1 : NEG_SLOPE*y1;
    v.z = y2 >= 0.f ? y2 : NEG_SLOPE*y2;
    v.w = y3 >= 0.f ? y3 : NEG_SLOPE*y3;
    *(float4*)&sel_out[base] = v;
}

extern "C" void kernel_launch(void* const* d_in, const int* in_sizes, int n_in,
                              void* d_out, int out_size, void* d_ws, size_t ws_size,
                              hipStream_t stream)
{
    const float* pos   = (const float*)d_in[0];
    const float* x     = (const float*)d_in[1];
    const float* W     = (const float*)d_in[2];
    const float* bias  = (const float*)d_in[3];
    const float* gamma = (const float*)d_in[4];
    const float* beta  = (const float*)d_in[5];
    float* out = (float*)d_out;
    char*  ws  = (char*)d_ws;

    // ws layout (~35.4 MB):
    // [0,2MB):    idx (1.25MB used)
    // [2MB,34MB): region X — first d_part(10.5MB)+j_part(10.5MB), then A(16MB)+B(16MB)
    //             (gemm runs AFTER merge, so A/B may overwrite the partials)
    // [34MB,..):  stats (5*COUT) + msc (2*COUT)
    // [35MB,..):  cand4 (256KB) then tau (64KB)
    int*   idx    = (int*)(ws);
    float* d_part = (float*)(ws + (2u<<20));
    int*   j_part = (int*)  (ws + (2u<<20) + (11u<<20));
    float* A      = (float*)(ws + (2u<<20));
    float* Bm     = (float*)(ws + (2u<<20) + (16u<<20));
    float* stats  = (float*)(ws + (34u<<20));
    float* msc    = stats + 5*COUT;
    float4* cand4 = (float4*)(ws + (35u<<20));
    float* tau    = (float*)(ws + (35u<<20) + (256u<<10));

    prep_kernel    <<<dim3(64),     dim3(256), 0, stream>>>(pos, cand4, tau);
    knn_main       <<<dim3(512),    dim3(256), 0, stream>>>(cand4, tau, d_part, j_part);
    knn_merge      <<<dim3(256),    dim3(64),  0, stream>>>(d_part, j_part, idx);
    gemm_kernel    <<<dim3(256, 8), dim3(256), 0, stream>>>(x, W, bias, A, Bm, stats);
    gather_kernel  <<<dim3(512),    dim3(256), 0, stream>>>(idx, A, Bm, gamma, out, stats);
    finalize_kernel<<<dim3(1),      dim3(256), 0, stream>>>(stats, gamma, msc);
    out_kernel     <<<dim3(4096),   dim3(256), 0, stream>>>(out, msc, beta);
}

// Round 8
// 758.073 us; speedup vs baseline: 1.3039x; 1.1009x over previous
//
#include <hip/hip_runtime.h>

#define N_PTS 16384
#define CIN 128
#define COUT 256
#define KNN 20
#define NKTOT (N_PTS*KNN)
#define NEG_SLOPE 0.2f
#define BN_EPS 1e-5f
#define S_SLICES 8
#define SLICE (N_PTS/S_SLICES)   // 2048
#define BATCH 8
#define BUF_D 32                  // per-lane LDS pending-hit buffer depth

// Branchless stable insert of (pd,pj) into ascending-sorted 20-entry list.
// Strict d-compare: equal-d goes after existing -> with j-ascending arrival
// order this is exact jax.lax.top_k lex semantics. valid=false -> no-op.
__device__ __forceinline__ void insert20(float pd, int pj, bool valid,
                                         float (&Ld)[KNN], int (&Lj)[KNN])
{
    bool c[KNN];
#pragma unroll
    for (int k = 0; k < KNN; ++k) c[k] = valid && (pd < Ld[k]);
#pragma unroll
    for (int k = KNN-1; k >= 1; --k){
        Ld[k] = c[k] ? (c[k-1] ? Ld[k-1] : pd) : Ld[k];
        Lj[k] = c[k] ? (c[k-1] ? Lj[k-1] : pj) : Lj[k];
    }
    Ld[0] = c[0] ? pd : Ld[0];
    Lj[0] = c[0] ? pj : Lj[0];
}

// ============================ prep: pack (x,y,z,|p|^2) + tau=INF ============================
__global__ __launch_bounds__(256) void prep_kernel(const float* __restrict__ pos,
                                                   float4* __restrict__ cand4,
                                                   float* __restrict__ tau)
{
    const int j = blockIdx.x*256 + threadIdx.x;
    const float cx = pos[j*3+0], cy = pos[j*3+1], cz = pos[j*3+2];
    cand4[j] = make_float4(cx, cy, cz, cx*cx + cy*cy + cz*cz);
    tau[j] = __builtin_inff();   // ws is 0xAA-poisoned -> must init
}

// ============================ KNN main: lane-per-query, LDS hit buffer ============================
// Wave = 64 queries (one per lane) x one slice of 2048 candidates.
// R7's 4-deep register FIFO retired ~1.5 items per 130-inst insert20 drain
// (fired when ANY of 64 lanes filled -> ~69 VALU inst/candidate measured).
// Now: hits append to a 32-deep per-lane LDS buffer (branchless ds_write every
// step, garbage writes to slot min(cnt,31) are clobbered/never read); flush
// runs only when some lane reaches BUF_D-BATCH, retiring ~24*64 items per
// insert20 sweep. Hot loop is ~13 straight-line VALU inst, no divergence.
// Exactness: push filter lim = min(tau-bound, own Ld[19]); every bound ever
// published is >= the query's global 20th distance, so every true top-20
// member passes strict < at scan time (ties measure-zero, as all prior rounds).
__global__ __launch_bounds__(256) void knn_main(const float4* __restrict__ cand4,
                                                float* __restrict__ tau,
                                                float* __restrict__ d_part,
                                                int*   __restrict__ j_part)
{
    __shared__ float2 buf[256*BUF_D];   // 64KB -> 2 blocks/CU
    const float FINF = __builtin_inff();
    const int tid  = threadIdx.x;
    const int lane = tid & 63;
    const int g    = blockIdx.x*4 + (tid >> 6);   // global wave id, 0..2047
    const int s    = g >> 8;                      // slice 0..7
    const int qb   = (g & 255) * 64;              // query base
    const int i    = qb + lane;                   // my query
    float2* mybuf  = &buf[tid*BUF_D];

    const float4 q4 = cand4[i];
    const float qx = q4.x, qy = q4.y, qz = q4.z, qsq = q4.w;

    float Ld[KNN]; int Lj[KNN];
#pragma unroll
    for (int k = 0; k < KNN; ++k){ Ld[k] = FINF; Lj[k] = 0x7FFFFFFF; }
    int cnt = 0;
    float thr = FINF;   // best cross-wave bound seen
    float lim = FINF;   // hoisted push filter = min(thr, Ld[19])

    const int j0 = s*SLICE;
    for (int tb = 0; tb < SLICE; tb += BATCH){
        if ((tb & 63) == 0 && tb){   // checkpoint: refresh cross-wave bound
            const float tv = *(volatile float*)&tau[i];  // stale = looser = safe
            thr = fminf(thr, tv);
            lim = fminf(thr, Ld[KNN-1]);
        }
        if (__any(cnt >= BUF_D - BATCH)){   // flush before buffer can overflow
            for (int k0 = 0; k0 < BUF_D; k0 += 8){
                if (!__any(k0 < cnt)) break;
                float2 v[8];
#pragma unroll
                for (int u = 0; u < 8; ++u) v[u] = mybuf[k0+u];   // issued together
#pragma unroll
                for (int u = 0; u < 8; ++u){
                    const bool valid = (k0+u) < cnt;
                    if (__any(valid && v[u].x < Ld[KNN-1]))
                        insert20(v[u].x, __float_as_int(v[u].y), valid, Ld, Lj);
                }
            }
            cnt = 0;
            const float mine = Ld[KNN-1];
            if (mine < thr) atomicMin((int*)&tau[i], __float_as_int(mine));
            lim = fminf(thr, mine);
        }
        const int jb = j0 + tb;
        float4 cp[BATCH];
#pragma unroll
        for (int u = 0; u < BATCH; ++u) cp[u] = cand4[jb + u];   // wave-uniform scalar loads
#pragma unroll
        for (int u = 0; u < BATCH; ++u){
            const int j = jb + u;
            const float dot = qx*cp[u].x + qy*cp[u].y + qz*cp[u].z;
            float d = (qsq + cp[u].w) - 2.0f*dot;   // exact reference expression
            d = (j == i) ? FINF : d;                // branchless self-exclusion
            const bool c = d < lim;
            mybuf[min(cnt, BUF_D-1)] = make_float2(d, __int_as_float(j));
            cnt += c ? 1 : 0;
        }
    }
    // final flush
    for (int k0 = 0; k0 < BUF_D; k0 += 8){
        if (!__any(k0 < cnt)) break;
        float2 v[8];
#pragma unroll
        for (int u = 0; u < 8; ++u) v[u] = mybuf[k0+u];
#pragma unroll
        for (int u = 0; u < 8; ++u){
            const bool valid = (k0+u) < cnt;
            if (__any(valid && v[u].x < Ld[KNN-1]))
                insert20(v[u].x, __float_as_int(v[u].y), valid, Ld, Lj);
        }
    }
    {   // final publish (helps laggard waves)
        const float mine = Ld[KNN-1];
        if (mine < thr) atomicMin((int*)&tau[i], __float_as_int(mine));
    }
    // store partials transposed: [s][k][q] -> coalesced across lanes
#pragma unroll
    for (int k = 0; k < KNN; ++k){
        d_part[(s*KNN + k)*N_PTS + i] = Ld[k];
        j_part[(s*KNN + k)*N_PTS + i] = Lj[k];
    }
}

// ============================ KNN merge: 8 sorted lists -> top-20 ============================
__global__ __launch_bounds__(64, 1) void knn_merge(const float* __restrict__ d_part,
                                                   const int*   __restrict__ j_part,
                                                   int* __restrict__ out_idx)
{
    const float FINF = __builtin_inff();
    const int q = blockIdx.x*64 + threadIdx.x;
    float Ld[KNN]; int Lj[KNN];
#pragma unroll
    for (int k = 0; k < KNN; ++k){ Ld[k] = FINF; Lj[k] = 0x7FFFFFFF; }
    for (int s = 0; s < S_SLICES; ++s){
        float pd[KNN]; int pj[KNN];
#pragma unroll
        for (int k = 0; k < KNN; ++k){
            pd[k] = d_part[(s*KNN + k)*N_PTS + q];
            pj[k] = j_part[(s*KNN + k)*N_PTS + q];
        }
#pragma unroll
        for (int k = 0; k < KNN; ++k){
            if (!__any(pd[k] < Ld[KNN-1])) break;   // sorted: rest of slice can't enter
            insert20(pd[k], pj[k], true, Ld, Lj);
        }
    }
#pragma unroll
    for (int k = 0; k < KNN; ++k) out_idx[q*KNN + k] = Lj[k];
}

// ============================ GEMM: A = x@W_top + b, B = x@W_bot ============================
__global__ __launch_bounds__(256) void gemm_kernel(const float* __restrict__ x,
                                                   const float* __restrict__ W,
                                                   const float* __restrict__ bias,
                                                   float* __restrict__ Aout,
                                                   float* __restrict__ Bout,
                                                   float* __restrict__ stats)
{
    if (blockIdx.x == 0 && blockIdx.y == 0){
        for (int s = threadIdx.x; s < 5*COUT; s += 256) stats[s] = 0.f;
    }
    __shared__ __align__(16) float xs[64][CIN+1];
    __shared__ __align__(16) float wt[CIN][64];
    const int tid = threadIdx.x;
    const int tx = tid & 15, ty = tid >> 4;
    const int m0 = blockIdx.x*64;
    const int n0 = blockIdx.y*64;

    for (int l=tid; l<64*CIN; l+=256){
        const int row = l >> 7, k = l & (CIN-1);
        xs[row][k] = x[(m0+row)*CIN + k];
    }
    for (int l=tid; l<CIN*64; l+=256){
        const int k = l >> 6, cc = l & 63;
        const int gc = n0 + cc;
        wt[k][cc] = (gc < COUT) ? W[k*COUT + gc] : W[(CIN+k)*COUT + (gc-COUT)];
    }
    __syncthreads();

    float acc[4][4] = {};
#pragma unroll 4
    for (int k=0;k<CIN;k++){
        const float a0 = xs[ty*4+0][k];
        const float a1 = xs[ty*4+1][k];
        const float a2 = xs[ty*4+2][k];
        const float a3 = xs[ty*4+3][k];
        const float4 bv = *(const float4*)&wt[k][tx*4];
        acc[0][0] += a0*bv.x; acc[0][1] += a0*bv.y; acc[0][2] += a0*bv.z; acc[0][3] += a0*bv.w;
        acc[1][0] += a1*bv.x; acc[1][1] += a1*bv.y; acc[1][2] += a1*bv.z; acc[1][3] += a1*bv.w;
        acc[2][0] += a2*bv.x; acc[2][1] += a2*bv.y; acc[2][2] += a2*bv.z; acc[2][3] += a2*bv.w;
        acc[3][0] += a3*bv.x; acc[3][1] += a3*bv.y; acc[3][2] += a3*bv.z; acc[3][3] += a3*bv.w;
    }
    const int colg = n0 + tx*4;
    if (colg < COUT){
        const float4 bb = *(const float4*)&bias[colg];
#pragma unroll
        for (int rr=0; rr<4; ++rr){
            const float4 v = make_float4(acc[rr][0]+bb.x, acc[rr][1]+bb.y,
                                         acc[rr][2]+bb.z, acc[rr][3]+bb.w);
            *(float4*)&Aout[(m0+ty*4+rr)*COUT + colg] = v;
        }
    } else {
        const int cb = colg - COUT;
#pragma unroll
        for (int rr=0; rr<4; ++rr){
            const float4 v = make_float4(acc[rr][0], acc[rr][1], acc[rr][2], acc[rr][3]);
            *(float4*)&Bout[(m0+ty*4+rr)*COUT + cb] = v;
        }
    }
}

// ============================ Gather + stats + SEL ============================
__global__ __launch_bounds__(256) void gather_kernel(const int* __restrict__ idx,
        const float* __restrict__ A, const float* __restrict__ B,
        const float* __restrict__ gamma,
        float* __restrict__ sel, float* __restrict__ stats)
{
    __shared__ int sidx[32*KNN];
    const int c  = threadIdx.x;
    const int i0 = blockIdx.x*32;
    for (int l=c; l<32*KNN; l+=256) sidx[l] = idx[i0*KNN + l];
    __syncthreads();
    const float g = gamma[c];
    const float FINF = __builtin_inff();
    float sA=0.f, sA2=0.f, cross=0.f, sB=0.f, sB2=0.f;
    for (int ii=0; ii<32; ++ii){
        float bmax=-FINF, bmin=FINF, bsum=0.f;
#pragma unroll
        for (int k=0;k<KNN;k++){
            const int j = sidx[ii*KNN+k];
            const float v = B[j*COUT + c];
            bmax = fmaxf(bmax, v);
            bmin = fminf(bmin, v);
            bsum += v;
            sB2 += v*v;
        }
        const int i = i0 + ii;
        const float a = A[i*COUT + c];
        sA += a; sA2 += a*a; cross += a*bsum; sB += bsum;
        sel[i*COUT + c] = a + (g >= 0.f ? bmax : bmin);
    }
    atomicAdd(&stats[0*COUT+c], sA);
    atomicAdd(&stats[1*COUT+c], sA2);
    atomicAdd(&stats[2*COUT+c], cross);
    atomicAdd(&stats[3*COUT+c], sB);
    atomicAdd(&stats[4*COUT+c], sB2);
}

// ============================ Finalize stats ============================
__global__ void finalize_kernel(const float* __restrict__ stats,
                                const float* __restrict__ gamma,
                                float* __restrict__ msc)
{
    const int c = threadIdx.x;
    const float sA  = stats[0*COUT+c];
    const float sA2 = stats[1*COUT+c];
    const float cr  = stats[2*COUT+c];
    const float sB  = stats[3*COUT+c];
    const float sB2 = stats[4*COUT+c];
    const float inv_nk = 1.0f / (float)NKTOT;
    const float mean = ((float)KNN*sA + sB) * inv_nk;
    const float eh2  = ((float)KNN*sA2 + 2.f*cr + sB2) * inv_nk;
    const float var  = eh2 - mean*mean;
    msc[c]        = mean;
    msc[COUT + c] = gamma[c] * rsqrtf(var + BN_EPS);
}

// ============================ BN + LeakyReLU (in place on d_out) ============================
__global__ __launch_bounds__(256) void out_kernel(float* __restrict__ sel_out,
                                                  const float* __restrict__ msc,
                                                  const float* __restrict__ beta)
{
    const int t = blockIdx.x*256 + threadIdx.x;
    const int base = t*4;
    const int c = base & (COUT-1);
    float4 v = *(const float4*)&sel_out[base];
    const float4 m  = *(const float4*)&msc[c];
    const float4 s  = *(const float4*)&msc[COUT + c];
    const float4 bt = *(const float4*)&beta[c];
    const float y0 = (v.x - m.x)*s.x + bt.x;
    const float y1 = (v.y - m.y)*s.y + bt.y;
    const float y2 = (v.z - m.z)*s.z + bt.z;
    const float y3 = (v.w - m.w)*s.w + bt.w;
    v.x = y0 >= 0.f ? y0 : NEG_SLOPE*y0;
    v.y = y1 >= 0.f ? y1 : NEG_SLOPE*y1;
    v.z = y2 >= 0.f ? y2 : NEG_SLOPE*y2;
    v.w = y3 >= 0.f ? y3 : NEG_SLOPE*y3;
    *(float4*)&sel_out[base] = v;
}

extern "C" void kernel_launch(void* const* d_in, const int* in_sizes, int n_in,
                              void* d_out, int out_size, void* d_ws, size_t ws_size,
                              hipStream_t stream)
{
    const float* pos   = (const float*)d_in[0];
    const float* x     = (const float*)d_in[1];
    const float* W     = (const float*)d_in[2];
    const float* bias  = (const float*)d_in[3];
    const float* gamma = (const float*)d_in[4];
    const float* beta  = (const float*)d_in[5];
    float* out = (float*)d_out;
    char*  ws  = (char*)d_ws;

    // ws layout (~35.4 MB):
    // [0,2MB):    idx (1.25MB used)
    // [2MB,34MB): region X — first d_part(10.5MB)+j_part(10.5MB), then A(16MB)+B(16MB)
    //             (gemm runs AFTER merge, so A/B may overwrite the partials)
    // [34MB,..):  stats (5*COUT) + msc (2*COUT)
    // [35MB,..):  cand4 (256KB) then tau (64KB)
    int*   idx    = (int*)(ws);
    float* d_part = (float*)(ws + (2u<<20));
    int*   j_part = (int*)  (ws + (2u<<20) + (11u<<20));
    float* A      = (float*)(ws + (2u<<20));
    float* Bm     = (float*)(ws + (2u<<20) + (16u<<20));
    float* stats  = (float*)(ws + (34u<<20));
    float* msc    = stats + 5*COUT;
    float4* cand4 = (float4*)(ws + (35u<<20));
    float* tau    = (float*)(ws + (35u<<20) + (256u<<10));

    prep_kernel    <<<dim3(64),     dim3(256), 0, stream>>>(pos, cand4, tau);
    knn_main       <<<dim3(512),    dim3(256), 0, stream>>>(cand4, tau, d_part, j_part);
    knn_merge      <<<dim3(256),    dim3(64),  0, stream>>>(d_part, j_part, idx);
    gemm_kernel    <<<dim3(256, 8), dim3(256), 0, stream>>>(x, W, bias, A, Bm, stats);
    gather_kernel  <<<dim3(512),    dim3(256), 0, stream>>>(idx, A, Bm, gamma, out, stats);
    finalize_kernel<<<dim3(1),      dim3(256), 0, stream>>>(stats, gamma, msc);
    out_kernel     <<<dim3(4096),   dim3(256), 0, stream>>>(out, msc, beta);
}